// Round 1
// 7475.555 us; speedup vs baseline: 2.4853x; 2.4853x over previous
//
#include <hip/hip_runtime.h>

#define BB 2
#define LL 2048
#define DS 128
#define DF 1024
#define NH 4
#define NP 3
#define VV 32000
#define FFH 4096   // FFN_MULT*DF
#define CTXD 2048  // 2*DF
#define RR (BB*LL) // 4096
#define NHDF (NH*DF)

enum { EPI_NONE=0, EPI_TANH=1, EPI_GELU=2, EPI_EXPM=3 };

// =====================================================================
// Legacy fp32 SIMT GEMM (kept: small-N gemms + full fallback path)
// =====================================================================
#define BM 128
#define BN 128
#define BK 8

template<int EPI, bool BETA, bool BT, bool TRI>
__global__ __launch_bounds__(256) void gemm_f32(
    const float* __restrict__ A, int lda, long sA,
    const float* __restrict__ B, int ldb, long sB,
    float* __restrict__ C, int ldc, long sC,
    int M, int N, int K,
    const float* __restrict__ bias,
    const float* __restrict__ m2s, long sM2,
    const float* __restrict__ log_tau)
{
    __shared__ __align__(16) float As[BK][BM];
    __shared__ __align__(16) float Bs[BK][BN];
    int z = blockIdx.z;
    A += (long)z * sA; B += (long)z * sB; C += (long)z * sC;
    const float* m2p = (EPI == EPI_EXPM) ? (m2s + (long)z * sM2) : nullptr;

    int m0 = blockIdx.y * BM;
    int n0 = blockIdx.x * BN;
    int tid = threadIdx.x;
    int tx = tid & 15, ty = tid >> 4;

    float acc[8][8];
    #pragma unroll
    for (int i = 0; i < 8; i++)
        #pragma unroll
        for (int j = 0; j < 8; j++) acc[i][j] = 0.f;

    int kEnd = K;
    if (TRI) { int km = m0 + BM; kEnd = km < K ? km : K; }

    int arow = tid >> 1, akk = (tid & 1) * 4;
    for (int k0 = 0; k0 < kEnd; k0 += BK) {
        float4 av = *(const float4*)(A + (long)(m0 + arow) * lda + k0 + akk);
        As[akk+0][arow] = av.x; As[akk+1][arow] = av.y;
        As[akk+2][arow] = av.z; As[akk+3][arow] = av.w;
        if (BT) {
            float4 bv = *(const float4*)(B + (long)(n0 + arow) * ldb + k0 + akk);
            Bs[akk+0][arow] = bv.x; Bs[akk+1][arow] = bv.y;
            Bs[akk+2][arow] = bv.z; Bs[akk+3][arow] = bv.w;
        } else {
            int brow = tid >> 5, bcol = (tid & 31) * 4;
            float4 bv = *(const float4*)(B + (long)(k0 + brow) * ldb + n0 + bcol);
            *(float4*)&Bs[brow][bcol] = bv;
        }
        __syncthreads();
        #pragma unroll
        for (int kk = 0; kk < BK; kk++) {
            float a[8], b[8];
            *(float4*)&a[0] = *(const float4*)&As[kk][ty*8];
            *(float4*)&a[4] = *(const float4*)&As[kk][ty*8+4];
            *(float4*)&b[0] = *(const float4*)&Bs[kk][tx*8];
            *(float4*)&b[4] = *(const float4*)&Bs[kk][tx*8+4];
            #pragma unroll
            for (int i = 0; i < 8; i++)
                #pragma unroll
                for (int j = 0; j < 8; j++)
                    acc[i][j] = fmaf(a[i], b[j], acc[i][j]);
        }
        __syncthreads();
    }

    float scale = 0.f;
    if (EPI == EPI_EXPM) scale = -0.5f * expf(-log_tau[0]);

    #pragma unroll
    for (int i = 0; i < 8; i++) {
        int row = m0 + ty*8 + i;
        float* cp = C + (long)row * ldc + n0 + tx*8;
        float out[8];
        #pragma unroll
        for (int j = 0; j < 8; j++) {
            float v = acc[i][j];
            int col = n0 + tx*8 + j;
            if (EPI == EPI_EXPM) {
                v = expf(scale * (v + m2p[col]));
            } else {
                if (bias) v += bias[col];
                if (EPI == EPI_TANH) v = tanhf(v);
                else if (EPI == EPI_GELU) v = 0.5f*v*(1.f + erff(v*0.70710678118654752f));
            }
            out[j] = v;
        }
        if (BETA) {
            float4 c0 = *(const float4*)(cp);
            float4 c1 = *(const float4*)(cp + 4);
            out[0]+=c0.x; out[1]+=c0.y; out[2]+=c0.z; out[3]+=c0.w;
            out[4]+=c1.x; out[5]+=c1.y; out[6]+=c1.z; out[7]+=c1.w;
        }
        *(float4*)cp       = make_float4(out[0],out[1],out[2],out[3]);
        *(float4*)(cp + 4) = make_float4(out[4],out[5],out[6],out[7]);
    }
}

// =====================================================================
// Shared small kernels
// =====================================================================
__global__ __launch_bounds__(256) void embed_kernel(
    const int* __restrict__ ids, const float* __restrict__ tok_mu,
    const float* __restrict__ tok_lv, const float* __restrict__ tok_ra,
    const float* __restrict__ tok_f, const float* __restrict__ pos_mu,
    float* __restrict__ mu, float* __restrict__ iv,
    float* __restrict__ alpha, float* __restrict__ feat)
{
    int r = blockIdx.x; int l = r % LL;
    int id = ids[r];
    int tid = threadIdx.x;
    for (int i = tid; i < DS; i += 256) {
        mu[(long)r*DS + i] = tok_mu[(long)id*DS + i] + pos_mu[(long)l*DS + i];
        iv[(long)r*DS + i] = expf(-tok_lv[(long)id*DS + i]);
    }
    for (int i = tid; i < DF; i += 256)
        feat[(long)r*DF + i] = tok_f[(long)id*DF + i];
    if (tid == 0) alpha[r] = 1.f/(1.f + expf(-tok_ra[id]));
}

__global__ __launch_bounds__(256) void alpha_kernel(
    const float* __restrict__ ctx, const float* __restrict__ agw,
    const float* __restrict__ agb, float* __restrict__ alpha)
{
    int r = blockIdx.x;
    const float* xr = ctx + (long)r*CTXD;
    __shared__ float red[256];
    int tid = threadIdx.x;
    float s = 0.f;
    for (int i = tid; i < CTXD; i += 256) s += xr[i]*agw[i];
    red[tid] = s; __syncthreads();
    for (int st = 128; st > 0; st >>= 1) { if (tid < st) red[tid] += red[tid+st]; __syncthreads(); }
    if (tid == 0) alpha[r] *= 1.f/(1.f + expf(-(red[0] + agb[0])));
}

__global__ __launch_bounds__(256) void ctx_kernel(
    const float* __restrict__ feat, const float* __restrict__ meaning, float* __restrict__ ctx)
{
    long i4 = (long)blockIdx.x * 256 + threadIdx.x;
    long r = i4 >> 9;
    long c4 = i4 & 511;
    const float4* src = (c4 < 256) ? (const float4*)(feat + r*DF) + c4
                                   : (const float4*)(meaning + r*DF) + (c4 - 256);
    ((float4*)ctx)[i4] = *src;
}

// =====================================================================
// Legacy (fp32-path) builders — used only by the fallback path
// =====================================================================
__global__ __launch_bounds__(128) void qbuild_kernel(
    const float* __restrict__ mu, const float* __restrict__ iv,
    float* __restrict__ Q, float* __restrict__ m2s)
{
    int r = blockIdx.x; int d = threadIdx.x;
    float ivd = iv[(long)r*DS + d];
    float m   = mu[(long)r*DS + d];
    Q[(long)r*256 + d]       = ivd;
    Q[(long)r*256 + 128 + d] = m * ivd;
    __shared__ float red[128];
    red[d] = m*m*ivd; __syncthreads();
    for (int s = 64; s > 0; s >>= 1) { if (d < s) red[d] += red[d+s]; __syncthreads(); }
    if (d == 0) m2s[r] = red[0];
}

__global__ __launch_bounds__(128) void pbuild_kernel(const float* __restrict__ q, float* __restrict__ P)
{
    int r = blockIdx.x; int d = threadIdx.x;
    float qv = q[(long)r*DS + d];
    P[(long)r*256 + d]       = qv*qv;
    P[(long)r*256 + 128 + d] = -2.f*qv;
}

__global__ __launch_bounds__(256) void scan_weights(float* __restrict__ Kmat, const float* __restrict__ alpha)
{
    int r = blockIdx.x;
    int b = r / LL, t = r % LL;
    float* row = Kmat + (long)r * LL;
    const float* al = alpha + (long)b * LL;
    int tid = threadIdx.x;
    int lane = tid & 63, wid = tid >> 6;
    __shared__ float wtot[4];
    float carry = 1.f;
    for (int j0 = 0; j0 < LL; j0 += 256) {
        int j = j0 + tid;
        if (j0 > t) { row[j] = 0.f; continue; }
        float eff = 0.f;
        if (j <= t) eff = fminf(al[j] * row[j], 1.f - 1e-6f);
        float om = 1.f - eff;
        float incl = om;
        #pragma unroll
        for (int d = 1; d < 64; d <<= 1) {
            float v = __shfl_up(incl, d);
            if (lane >= d) incl *= v;
        }
        if (lane == 63) wtot[wid] = incl;
        float excl = __shfl_up(incl, 1);
        if (lane == 0) excl = 1.f;
        __syncthreads();
        float wpre = carry;
        for (int w = 0; w < wid; w++) wpre *= wtot[w];
        row[j] = eff * wpre * excl;
        float tot = wtot[0]*wtot[1]*wtot[2]*wtot[3];
        __syncthreads();
        carry *= tot;
    }
}

template<int C>
__global__ __launch_bounds__(256) void ln_kernel(
    const float* __restrict__ x, const float* __restrict__ g,
    const float* __restrict__ b, float* __restrict__ y)
{
    int r = blockIdx.x;
    const float* xr = x + (long)r*C;
    __shared__ float xs[C];
    __shared__ float red[256];
    int tid = threadIdx.x;
    float s = 0.f;
    for (int i = tid; i < C; i += 256) { float v = xr[i]; xs[i] = v; s += v; }
    red[tid] = s; __syncthreads();
    for (int st = 128; st > 0; st >>= 1) { if (tid < st) red[tid] += red[tid+st]; __syncthreads(); }
    float mean = red[0] / C;
    __syncthreads();
    float s2 = 0.f;
    for (int i = tid; i < C; i += 256) { float d = xs[i]-mean; s2 += d*d; }
    red[tid] = s2; __syncthreads();
    for (int st = 128; st > 0; st >>= 1) { if (tid < st) red[tid] += red[tid+st]; __syncthreads(); }
    float rs = rsqrtf(red[0]/C + 1e-5f);
    for (int i = tid; i < C; i += 256) y[(long)r*C + i] = (xs[i]-mean)*rs*g[i] + b[i];
}

// =====================================================================
// NEW: split-bf16 (hi+lo) MFMA path.
// fp32 x = hi + lo with two RNE bf16s; a*b ~= ah*bh + ah*bl + al*bh
// (dropped lo*lo <= 2^-18 |ab|) accumulated in fp32 by MFMA.
// =====================================================================
typedef __attribute__((ext_vector_type(8))) short bf8;   // 8 bf16 = 4 VGPRs
typedef __attribute__((ext_vector_type(4))) float f4;    // C/D frag

__device__ __forceinline__ unsigned short bf16_rne(float x){
    unsigned u = __builtin_bit_cast(unsigned, x);
    u += 0x7FFFu + ((u >> 16) & 1u);
    return (unsigned short)(u >> 16);
}
__device__ __forceinline__ float bf16f(unsigned short h){
    unsigned u = ((unsigned)h) << 16;
    return __builtin_bit_cast(float, u);
}
__device__ __forceinline__ void split2(float x, unsigned short& h, unsigned short& l){
    h = bf16_rne(x);
    l = bf16_rne(x - bf16f(h));
}
__device__ __forceinline__ f4 mfma_b(bf8 a, bf8 b, f4 c){
    return __builtin_amdgcn_mfma_f32_16x16x32_bf16(a, b, c, 0, 0, 0);
}

// Split-bf16 GEMM. A: [M,K] planes (Ah,Al). B: [N,K] planes (i.e. always "BT").
// C fp32 (optional BETA accumulate) or OSPLIT: write hi/lo bf16 planes.
// TRI: skip k-tiles with k0 >= m0+128 (A upper region is zero-filled).
// 128x128 tile, BK=32, 256 thr (2x2 waves of 64x64), mfma 16x16x32 bf16.
template<int EPI, bool BETA, bool TRI, bool OSPLIT>
__global__ __launch_bounds__(256, 2) void gemm_mf(
    const unsigned short* __restrict__ Ah, const unsigned short* __restrict__ Al, int lda, long sA,
    const unsigned short* __restrict__ Bh, const unsigned short* __restrict__ Bl, int ldb, long sB,
    float* __restrict__ C, unsigned short* __restrict__ Ch, unsigned short* __restrict__ Cl,
    int ldc, long sC, int M, int N, int K,
    const float* __restrict__ bias, const float* __restrict__ m2s, long sM2,
    const float* __restrict__ log_tau)
{
    // [plane: Ah,Al,Bh,Bl][k-chunk 0..3][row 0..127][8 bf16] — 32 KiB
    __shared__ __align__(16) unsigned short lds[4][4][128][8];

    int z = blockIdx.z;
    Ah += (long)z * sA; Al += (long)z * sA;
    Bh += (long)z * sB; Bl += (long)z * sB;
    if (OSPLIT) { Ch += (long)z * sC; Cl += (long)z * sC; }
    else        { C  += (long)z * sC; }
    const float* m2p = (EPI == EPI_EXPM) ? (m2s + (long)z * sM2) : nullptr;

    int m0 = blockIdx.y * 128, n0 = blockIdx.x * 128;
    int tid  = threadIdx.x;
    int lane = tid & 63, wave = tid >> 6;
    int wm = wave >> 1, wn = wave & 1;       // 2x2 waves, each 64x64 output
    int kc = lane >> 4, lr = lane & 15;      // frag k-chunk / row-col select

    f4 acc[4][4];
    #pragma unroll
    for (int i = 0; i < 4; i++)
        #pragma unroll
        for (int j = 0; j < 4; j++)
            #pragma unroll
            for (int r = 0; r < 4; r++) acc[i][j][r] = 0.f;

    int kEnd = K;
    if (TRI) { int km = m0 + 128; kEnd = km < K ? km : K; }

    int s0 = tid, s1 = tid + 256;            // 512 16B-slots per plane
    int row0 = s0 & 127, c0 = s0 >> 7;
    int row1 = s1 & 127, c1 = s1 >> 7;

    for (int kt = 0; kt < kEnd; kt += 32) {
        long a0 = (long)(m0 + row0) * lda + kt + c0 * 8;
        long a1 = (long)(m0 + row1) * lda + kt + c1 * 8;
        long b0 = (long)(n0 + row0) * ldb + kt + c0 * 8;
        long b1 = (long)(n0 + row1) * ldb + kt + c1 * 8;
        uint4 vah0 = *(const uint4*)(Ah + a0);
        uint4 vah1 = *(const uint4*)(Ah + a1);
        uint4 val0 = *(const uint4*)(Al + a0);
        uint4 val1 = *(const uint4*)(Al + a1);
        uint4 vbh0 = *(const uint4*)(Bh + b0);
        uint4 vbh1 = *(const uint4*)(Bh + b1);
        uint4 vbl0 = *(const uint4*)(Bl + b0);
        uint4 vbl1 = *(const uint4*)(Bl + b1);
        *(uint4*)&lds[0][c0][row0][0] = vah0;
        *(uint4*)&lds[0][c1][row1][0] = vah1;
        *(uint4*)&lds[1][c0][row0][0] = val0;
        *(uint4*)&lds[1][c1][row1][0] = val1;
        *(uint4*)&lds[2][c0][row0][0] = vbh0;
        *(uint4*)&lds[2][c1][row1][0] = vbh1;
        *(uint4*)&lds[3][c0][row0][0] = vbl0;
        *(uint4*)&lds[3][c1][row1][0] = vbl1;
        __syncthreads();

        bf8 ah[4], al4[4], bh4[4], bl4[4];
        #pragma unroll
        for (int i = 0; i < 4; i++) {
            ah[i]  = *(const bf8*)&lds[0][kc][wm*64 + i*16 + lr][0];
            al4[i] = *(const bf8*)&lds[1][kc][wm*64 + i*16 + lr][0];
            bh4[i] = *(const bf8*)&lds[2][kc][wn*64 + i*16 + lr][0];
            bl4[i] = *(const bf8*)&lds[3][kc][wn*64 + i*16 + lr][0];
        }
        #pragma unroll
        for (int i = 0; i < 4; i++)
            #pragma unroll
            for (int j = 0; j < 4; j++) {
                acc[i][j] = mfma_b(ah[i],  bh4[j], acc[i][j]);
                acc[i][j] = mfma_b(al4[i], bh4[j], acc[i][j]);
                acc[i][j] = mfma_b(ah[i],  bl4[j], acc[i][j]);
            }
        __syncthreads();
    }

    float scale = 0.f;
    if (EPI == EPI_EXPM) scale = -0.5f * expf(-log_tau[0]);
    int r0 = (lane >> 4) * 4;
    #pragma unroll
    for (int i = 0; i < 4; i++) {
        int rowb = m0 + wm*64 + i*16 + r0;
        #pragma unroll
        for (int j = 0; j < 4; j++) {
            int col = n0 + wn*64 + j*16 + lr;
            float bv = 0.f, m2v = 0.f;
            if (EPI == EPI_EXPM) m2v = m2p[col];
            else if (bias) bv = bias[col];
            #pragma unroll
            for (int r = 0; r < 4; r++) {
                long off = (long)(rowb + r) * ldc + col;
                float v = acc[i][j][r];
                if (EPI == EPI_EXPM) v = expf(scale * (v + m2v));
                else {
                    v += bv;
                    if (EPI == EPI_TANH) v = tanhf(v);
                    else if (EPI == EPI_GELU) v = 0.5f*v*(1.f + erff(v*0.70710678118654752f));
                }
                if (OSPLIT) {
                    unsigned short hh, llo; split2(v, hh, llo);
                    Ch[off] = hh; Cl[off] = llo;
                } else {
                    if (BETA) v += C[off];
                    C[off] = v;
                }
            }
        }
    }
}

// plain fp32 -> (hi,lo) bf16 planes; n must be multiple of 1024; grid = n/1024
__global__ __launch_bounds__(256) void split_kernel(
    const float* __restrict__ x, unsigned short* __restrict__ h, unsigned short* __restrict__ l)
{
    long i = (long)blockIdx.x * 256 + threadIdx.x;
    float4 v = ((const float4*)x)[i];
    ushort4 hv, lv;
    split2(v.x, hv.x, lv.x); split2(v.y, hv.y, lv.y);
    split2(v.z, hv.z, lv.z); split2(v.w, hv.w, lv.w);
    ((ushort4*)h)[i] = hv;
    ((ushort4*)l)[i] = lv;
}

// feat [RR,DF] fp32 -> featT hi/lo planes [DF,RR]; grid (DF/32, RR/32), 256 thr
__global__ __launch_bounds__(256) void tsplit_kernel(
    const float* __restrict__ x, unsigned short* __restrict__ th, unsigned short* __restrict__ tl)
{
    __shared__ float t[32][33];
    int bx = blockIdx.x, by = blockIdx.y;
    int tx = threadIdx.x & 31, ty = threadIdx.x >> 5;
    #pragma unroll
    for (int k = 0; k < 4; k++)
        t[ty + 8*k][tx] = x[(long)(by*32 + ty + 8*k)*DF + bx*32 + tx];
    __syncthreads();
    #pragma unroll
    for (int k = 0; k < 4; k++) {
        float v = t[tx][ty + 8*k];
        unsigned short hh, llo; split2(v, hh, llo);
        long o = (long)(bx*32 + ty + 8*k)*RR + by*32 + tx;
        th[o] = hh; tl[o] = llo;
    }
}

__global__ __launch_bounds__(128) void qbuild_mf(
    const float* __restrict__ mu, const float* __restrict__ iv,
    unsigned short* __restrict__ Qh, unsigned short* __restrict__ Ql,
    float* __restrict__ m2s)
{
    int r = blockIdx.x; int d = threadIdx.x;
    float ivd = iv[(long)r*DS + d];
    float m   = mu[(long)r*DS + d];
    unsigned short hh, llo;
    split2(ivd, hh, llo);
    Qh[(long)r*256 + d] = hh;        Ql[(long)r*256 + d] = llo;
    split2(m * ivd, hh, llo);
    Qh[(long)r*256 + 128 + d] = hh;  Ql[(long)r*256 + 128 + d] = llo;
    __shared__ float red[128];
    red[d] = m*m*ivd; __syncthreads();
    for (int s = 64; s > 0; s >>= 1) { if (d < s) red[d] += red[d+s]; __syncthreads(); }
    if (d == 0) m2s[r] = red[0];
}

__global__ __launch_bounds__(128) void pbuild_mf(
    const float* __restrict__ q,
    unsigned short* __restrict__ Ph, unsigned short* __restrict__ Pl)
{
    int r = blockIdx.x; int d = threadIdx.x;
    float qv = q[(long)r*DS + d];
    unsigned short hh, llo;
    split2(qv*qv, hh, llo);
    Ph[(long)r*256 + d] = hh;        Pl[(long)r*256 + d] = llo;
    split2(-2.f*qv, hh, llo);
    Ph[(long)r*256 + 128 + d] = hh;  Pl[(long)r*256 + 128 + d] = llo;
}

// stick-breaking scan; reads fp32 K, writes hi/lo bf16 weight planes
__global__ __launch_bounds__(256) void scan_weights_mf(
    const float* __restrict__ Kmat, const float* __restrict__ alpha,
    unsigned short* __restrict__ Wh, unsigned short* __restrict__ Wl)
{
    int r = blockIdx.x;
    int b = r / LL, t = r % LL;
    const float* row = Kmat + (long)r * LL;
    unsigned short* wh = Wh + (long)r * LL;
    unsigned short* wl = Wl + (long)r * LL;
    const float* al = alpha + (long)b * LL;
    int tid = threadIdx.x;
    int lane = tid & 63, wid = tid >> 6;
    __shared__ float wtot[4];
    float carry = 1.f;
    for (int j0 = 0; j0 < LL; j0 += 256) {
        int j = j0 + tid;
        if (j0 > t) { wh[j] = 0; wl[j] = 0; continue; }   // block-uniform
        float eff = 0.f;
        if (j <= t) eff = fminf(al[j] * row[j], 1.f - 1e-6f);
        float om = 1.f - eff;
        float incl = om;
        #pragma unroll
        for (int d = 1; d < 64; d <<= 1) {
            float v = __shfl_up(incl, d);
            if (lane >= d) incl *= v;
        }
        if (lane == 63) wtot[wid] = incl;
        float excl = __shfl_up(incl, 1);
        if (lane == 0) excl = 1.f;
        __syncthreads();
        float wpre = carry;
        for (int w = 0; w < wid; w++) wpre *= wtot[w];
        float val = eff * wpre * excl;
        unsigned short hh, llo; split2(val, hh, llo);
        wh[j] = hh; wl[j] = llo;
        float tot = wtot[0]*wtot[1]*wtot[2]*wtot[3];
        __syncthreads();
        carry *= tot;
    }
}

// layernorm -> hi/lo bf16 planes
template<int C>
__global__ __launch_bounds__(256) void ln_mf(
    const float* __restrict__ x, const float* __restrict__ g,
    const float* __restrict__ b, unsigned short* __restrict__ yh, unsigned short* __restrict__ yl)
{
    int r = blockIdx.x;
    const float* xr = x + (long)r*C;
    __shared__ float xs[C];
    __shared__ float red[256];
    int tid = threadIdx.x;
    float s = 0.f;
    for (int i = tid; i < C; i += 256) { float v = xr[i]; xs[i] = v; s += v; }
    red[tid] = s; __syncthreads();
    for (int st = 128; st > 0; st >>= 1) { if (tid < st) red[tid] += red[tid+st]; __syncthreads(); }
    float mean = red[0] / C;
    __syncthreads();
    float s2 = 0.f;
    for (int i = tid; i < C; i += 256) { float d = xs[i]-mean; s2 += d*d; }
    red[tid] = s2; __syncthreads();
    for (int st = 128; st > 0; st >>= 1) { if (tid < st) red[tid] += red[tid+st]; __syncthreads(); }
    float rs = rsqrtf(red[0]/C + 1e-5f);
    for (int i = tid; i < C; i += 256) {
        float v = (xs[i]-mean)*rs*g[i] + b[i];
        unsigned short hh, llo; split2(v, hh, llo);
        yh[(long)r*C + i] = hh; yl[(long)r*C + i] = llo;
    }
}

// =====================================================================
// Legacy launch (verbatim previous-best path) — fallback if ws too small
// =====================================================================
static void launch_legacy(void* const* d_in, void* d_out, void* d_ws, hipStream_t stream)
{
    const int*   token_ids = (const int*)d_in[0];
    const float* tok_mu  = (const float*)d_in[1];
    const float* tok_lv  = (const float*)d_in[2];
    const float* tok_ra  = (const float*)d_in[3];
    const float* tok_f   = (const float*)d_in[4];
    const float* pos_mu  = (const float*)d_in[5];
    const float* log_tau = (const float*)d_in[6];
    const float* qp_w = (const float*)d_in[7];
    const float* qp_b = (const float*)d_in[8];
    const float* hp_w = (const float*)d_in[9];
    const float* hp_b = (const float*)d_in[10];
    const float* mu_w = (const float*)d_in[11];
    const float* mu_b = (const float*)d_in[12];
    const float* ag_w = (const float*)d_in[13];
    const float* ag_b = (const float*)d_in[14];
    const float* ln_g = (const float*)d_in[15];
    const float* ln_b = (const float*)d_in[16];
    const float* w1 = (const float*)d_in[17];
    const float* b1 = (const float*)d_in[18];
    const float* w2 = (const float*)d_in[19];
    const float* b2 = (const float*)d_in[20];
    const float* lnf_g = (const float*)d_in[21];
    const float* lnf_b = (const float*)d_in[22];
    const float* lm_w  = (const float*)d_in[23];
    float* out = (float*)d_out;

    float* ws      = (float*)d_ws;
    float* mu      = ws;
    float* iv      = mu + 524288;
    float* alpha   = iv + 524288;
    float* m2s     = alpha + 4096;
    float* q       = m2s + 4096;
    float* P       = q + 524288;
    float* Q       = P + 1048576;
    float* feat    = Q + 1048576;
    float* meaning = feat + 4194304;
    float* head_m  = meaning + 4194304;
    float* ctx     = head_m + 4194304;
    float* Kbuf    = ctx + 8388608;
    float* h1  = Kbuf;
    float* h2  = head_m;
    float* lnm = head_m;

    const int R = BB * LL;

    embed_kernel<<<R, 256, 0, stream>>>(token_ids, tok_mu, tok_lv, tok_ra, tok_f, pos_mu,
                                        mu, iv, alpha, feat);

    for (int p = 0; p < NP; p++) {
        qbuild_kernel<<<R, 128, 0, stream>>>(mu, iv, Q, m2s);
        for (int h = 0; h < NH; h++) {
            dim3 g1(DS/BN, R/BM, 1);
            gemm_f32<EPI_NONE,false,true,false><<<g1,256,0,stream>>>(
                mu, DS, 0, qp_w + (long)h*DS*DS, DS, 0, q, DS, 0,
                R, DS, DS, qp_b + h*DS, nullptr, 0, nullptr);
            pbuild_kernel<<<R, 128, 0, stream>>>(q, P);
            dim3 g2(LL/BN, LL/BM, BB);
            gemm_f32<EPI_EXPM,false,true,false><<<g2,256,0,stream>>>(
                P, 256, (long)LL*256, Q, 256, (long)LL*256, Kbuf, LL, (long)LL*LL,
                LL, LL, 256, nullptr, m2s, LL, log_tau);
            scan_weights<<<R, 256, 0, stream>>>(Kbuf, alpha);
            dim3 g3(DF/BN, LL/BM, BB);
            gemm_f32<EPI_NONE,false,false,true><<<g3,256,0,stream>>>(
                Kbuf, LL, (long)LL*LL, feat, DF, (long)LL*DF, head_m, DF, (long)LL*DF,
                LL, DF, LL, nullptr, nullptr, 0, nullptr);
            dim3 g4(DF/BN, R/BM, 1);
            if (h == 0)
                gemm_f32<EPI_NONE,false,true,false><<<g4,256,0,stream>>>(
                    head_m, DF, 0, hp_w + (long)h*DF, NH*DF, 0, meaning, DF, 0,
                    R, DF, DF, hp_b, nullptr, 0, nullptr);
            else
                gemm_f32<EPI_NONE,true,true,false><<<g4,256,0,stream>>>(
                    head_m, DF, 0, hp_w + (long)h*DF, NH*DF, 0, meaning, DF, 0,
                    R, DF, DF, nullptr, nullptr, 0, nullptr);
        }
        if (p < NP - 1) {
            ctx_kernel<<<(R*CTXD/4)/256, 256, 0, stream>>>(feat, meaning, ctx);
            dim3 g5(DS/BN, R/BM, 1);
            gemm_f32<EPI_TANH,true,true,false><<<g5,256,0,stream>>>(
                ctx, CTXD, 0, mu_w + (long)p*DS*CTXD, CTXD, 0, mu, DS, 0,
                R, DS, CTXD, mu_b + p*DS, nullptr, 0, nullptr);
            alpha_kernel<<<R, 256, 0, stream>>>(ctx, ag_w + (long)p*CTXD, ag_b + p, alpha);
            ln_kernel<CTXD><<<R, 256, 0, stream>>>(ctx, ln_g + (long)p*CTXD, ln_b + (long)p*CTXD, h1);
            for (int c = 0; c < 4; c++) {
                long ro = (long)c * 1024;
                dim3 g6(FFH/BN, 1024/BM, 1);
                gemm_f32<EPI_GELU,false,true,false><<<g6,256,0,stream>>>(
                    h1 + ro*CTXD, CTXD, 0, w1 + (long)p*FFH*CTXD, CTXD, 0, h2, FFH, 0,
                    1024, FFH, CTXD, b1 + (long)p*FFH, nullptr, 0, nullptr);
                dim3 g7(DF/BN, 1024/BM, 1);
                gemm_f32<EPI_NONE,true,true,false><<<g7,256,0,stream>>>(
                    h2, FFH, 0, w2 + (long)p*DF*FFH, FFH, 0, feat + ro*DF, DF, 0,
                    1024, DF, FFH, b2 + (long)p*DF, nullptr, 0, nullptr);
            }
        }
    }

    ln_kernel<DF><<<R, 256, 0, stream>>>(meaning, lnf_g, lnf_b, lnm);
    dim3 g8(VV/BN, R/BM, 1);
    gemm_f32<EPI_NONE,false,true,false><<<g8,256,0,stream>>>(
        lnm, DF, 0, lm_w, DF, 0, out, VV, 0,
        R, VV, DF, nullptr, nullptr, 0, nullptr);
}

// =====================================================================
// New MFMA launch
// =====================================================================
extern "C" void kernel_launch(void* const* d_in, const int* in_sizes, int n_in,
                              void* d_out, int out_size, void* d_ws, size_t ws_size,
                              hipStream_t stream)
{
    // workspace: fp32 region 73,433,088 B + bf16 pool 100,663,296 B
    const size_t WS_NEED = 174096384;
    if (ws_size < WS_NEED) {          // unknown ws cap -> safe fallback
        launch_legacy(d_in, d_out, d_ws, stream);
        return;
    }

    const int*   token_ids = (const int*)d_in[0];
    const float* tok_mu  = (const float*)d_in[1];
    const float* tok_lv  = (const float*)d_in[2];
    const float* tok_ra  = (const float*)d_in[3];
    const float* tok_f   = (const float*)d_in[4];
    const float* pos_mu  = (const float*)d_in[5];
    const float* log_tau = (const float*)d_in[6];
    const float* qp_w = (const float*)d_in[7];
    const float* qp_b = (const float*)d_in[8];
    const float* hp_w = (const float*)d_in[9];
    const float* hp_b = (const float*)d_in[10];
    const float* mu_w = (const float*)d_in[11];
    const float* mu_b = (const float*)d_in[12];
    const float* ag_w = (const float*)d_in[13];
    const float* ag_b = (const float*)d_in[14];
    const float* ln_g = (const float*)d_in[15];
    const float* ln_b = (const float*)d_in[16];
    const float* w1 = (const float*)d_in[17];
    const float* b1 = (const float*)d_in[18];
    const float* w2 = (const float*)d_in[19];
    const float* b2 = (const float*)d_in[20];
    const float* lnf_g = (const float*)d_in[21];
    const float* lnf_b = (const float*)d_in[22];
    const float* lm_w  = (const float*)d_in[23];
    float* out = (float*)d_out;

    // ---- fp32 region (18,358,272 floats) ----
    float* ws      = (float*)d_ws;
    float* mu      = ws;                       // 524288
    float* iv      = mu + 524288;              // 524288
    float* alpha   = iv + 524288;              // 4096
    float* m2s     = alpha + 4096;             // 4096
    float* q       = m2s + 4096;               // 524288
    float* feat    = q + 524288;               // 4194304
    float* meaning = feat + 4194304;           // 4194304
    float* ctxK    = meaning + 4194304;        // 8388608  union: ctx (pass tail) / Kbuf (head loop)
    float* Kbuf = ctxK;
    float* ctx  = ctxK;

    // ---- bf16 pool (50,331,648 ushorts), phase-aliased ----
    unsigned short* pool = (unsigned short*)(ctxK + 8388608);
    // head phase
    unsigned short* featT_h = pool;                 // 4194304  [DF,RR]
    unsigned short* featT_l = pool + 4194304;
    unsigned short* hpw_h   = pool + 8388608;       // 4194304  [DF,NHDF]
    unsigned short* hpw_l   = pool + 12582912;
    unsigned short* P_h     = pool + 16777216;      // 1048576  [RR,256]
    unsigned short* P_l     = pool + 17825792;
    unsigned short* Q_h     = pool + 18874368;      // 1048576
    unsigned short* Q_l     = pool + 19922944;
    unsigned short* W_h     = pool + 20971520;      // 8388608  [BB,LL,LL]
    unsigned short* W_l     = pool + 29360128;
    unsigned short* hm_h    = pool + 37748736;      // 4194304  [RR,DF]
    unsigned short* hm_l    = pool + 41943040;
    // ffn phase (aliases head phase — featT/hpw are rebuilt each pass)
    unsigned short* h1_h  = pool;                   // 4194304  [2048,CTXD]
    unsigned short* h1_l  = pool + 4194304;
    unsigned short* w1s_h = pool + 8388608;         // 8388608  [FFH,CTXD]
    unsigned short* w1s_l = pool + 16777216;
    unsigned short* h2_h  = pool + 25165824;        // 8388608  [2048,FFH]
    unsigned short* h2_l  = pool + 33554432;
    unsigned short* w2s_h = pool + 41943040;        // 4194304  [DF,FFH]
    unsigned short* w2s_l = pool + 46137344;
    // end phase
    unsigned short* lnm_h = pool;                   // 4194304  [RR,DF]
    unsigned short* lnm_l = pool + 4194304;
    unsigned short* lmw_h = pool + 8388608;         // 16384000 [16000,DF]
    unsigned short* lmw_l = pool + 24772608;

    embed_kernel<<<RR, 256, 0, stream>>>(token_ids, tok_mu, tok_lv, tok_ra, tok_f, pos_mu,
                                         mu, iv, alpha, feat);

    for (int p = 0; p < NP; p++) {
        tsplit_kernel<<<dim3(DF/32, RR/32), 256, 0, stream>>>(feat, featT_h, featT_l);
        split_kernel<<<(DF*NHDF)/1024, 256, 0, stream>>>(hp_w, hpw_h, hpw_l);
        qbuild_mf<<<RR, 128, 0, stream>>>(mu, iv, Q_h, Q_l, m2s);
        for (int h = 0; h < NH; h++) {
            // q = mu @ qp_w[h]^T + qp_b[h]   (small, fp32 SIMT)
            dim3 g1(DS/BN, RR/BM, 1);
            gemm_f32<EPI_NONE,false,true,false><<<g1,256,0,stream>>>(
                mu, DS, 0, qp_w + (long)h*DS*DS, DS, 0, q, DS, 0,
                RR, DS, DS, qp_b + h*DS, nullptr, 0, nullptr);
            pbuild_mf<<<RR, 128, 0, stream>>>(q, P_h, P_l);
            // K = exp(-0.5*(P@Q^T + m2s[j])/tau), batched over b
            dim3 g2(LL/128, LL/128, BB);
            gemm_mf<EPI_EXPM,false,false,false><<<g2,256,0,stream>>>(
                P_h, P_l, 256, (long)LL*256, Q_h, Q_l, 256, (long)LL*256,
                Kbuf, nullptr, nullptr, LL, (long)LL*LL,
                LL, LL, 256, nullptr, m2s, LL, log_tau);
            scan_weights_mf<<<RR, 256, 0, stream>>>(Kbuf, alpha, W_h, W_l);
            // head_m = W @ features  (via featT planes; causal k-skip) -> split planes
            dim3 g3(DF/128, LL/128, BB);
            gemm_mf<EPI_NONE,false,true,true><<<g3,256,0,stream>>>(
                W_h, W_l, LL, (long)LL*LL, featT_h, featT_l, RR, (long)LL,
                nullptr, hm_h, hm_l, DF, (long)LL*DF,
                LL, DF, LL, nullptr, nullptr, 0, nullptr);
            // meaning (+)= head_m @ hp_w[:, h*DF:(h+1)*DF]^T (+ hp_b at h==0)
            dim3 g4(DF/128, RR/128, 1);
            if (h == 0)
                gemm_mf<EPI_NONE,false,false,false><<<g4,256,0,stream>>>(
                    hm_h, hm_l, DF, 0, hpw_h + (long)h*DF, hpw_l + (long)h*DF, NHDF, 0,
                    meaning, nullptr, nullptr, DF, 0,
                    RR, DF, DF, hp_b, nullptr, 0, nullptr);
            else
                gemm_mf<EPI_NONE,true,false,false><<<g4,256,0,stream>>>(
                    hm_h, hm_l, DF, 0, hpw_h + (long)h*DF, hpw_l + (long)h*DF, NHDF, 0,
                    meaning, nullptr, nullptr, DF, 0,
                    RR, DF, DF, nullptr, nullptr, 0, nullptr);
        }
        if (p < NP - 1) {
            ctx_kernel<<<(RR*CTXD/4)/256, 256, 0, stream>>>(feat, meaning, ctx);
            // mu += tanh(ctx @ mu_w[p]^T + mu_b[p])  (N=128, fp32 SIMT)
            dim3 g5(DS/BN, RR/BM, 1);
            gemm_f32<EPI_TANH,true,true,false><<<g5,256,0,stream>>>(
                ctx, CTXD, 0, mu_w + (long)p*DS*CTXD, CTXD, 0, mu, DS, 0,
                RR, DS, CTXD, mu_b + p*DS, nullptr, 0, nullptr);
            alpha_kernel<<<RR, 256, 0, stream>>>(ctx, ag_w + (long)p*CTXD, ag_b + p, alpha);
            split_kernel<<<(FFH*CTXD)/1024, 256, 0, stream>>>(w1 + (long)p*FFH*CTXD, w1s_h, w1s_l);
            split_kernel<<<(DF*FFH)/1024, 256, 0, stream>>>(w2 + (long)p*DF*FFH, w2s_h, w2s_l);
            // FFN in 2048-row chunks (w1 grid 512 blocks, w2 grid 128 blocks)
            for (int c = 0; c < 2; c++) {
                long ro = (long)c * 2048;
                ln_mf<CTXD><<<2048, 256, 0, stream>>>(
                    ctx + ro*CTXD, ln_g + (long)p*CTXD, ln_b + (long)p*CTXD, h1_h, h1_l);
                dim3 g6(FFH/128, 2048/128, 1);
                gemm_mf<EPI_GELU,false,false,true><<<g6,256,0,stream>>>(
                    h1_h, h1_l, CTXD, 0, w1s_h, w1s_l, CTXD, 0,
                    nullptr, h2_h, h2_l, FFH, 0,
                    2048, FFH, CTXD, b1 + (long)p*FFH, nullptr, 0, nullptr);
                dim3 g7(DF/128, 2048/128, 1);
                gemm_mf<EPI_NONE,true,false,false><<<g7,256,0,stream>>>(
                    h2_h, h2_l, FFH, 0, w2s_h, w2s_l, FFH, 0,
                    feat + ro*DF, nullptr, nullptr, DF, 0,
                    2048, DF, FFH, b2 + (long)p*DF, nullptr, 0, nullptr);
            }
        }
    }

    // logits = LN(meaning) @ lm_w^T, in 2 N-chunks of 16000 (lmw split buffer reuse)
    ln_mf<DF><<<RR, 256, 0, stream>>>(meaning, lnf_g, lnf_b, lnm_h, lnm_l);
    for (int c = 0; c < 2; c++) {
        split_kernel<<<(16000*DF)/1024, 256, 0, stream>>>(lm_w + (long)c*16000*DF, lmw_h, lmw_l);
        dim3 g8(16000/128, RR/128, 1);
        gemm_mf<EPI_NONE,false,false,false><<<g8,256,0,stream>>>(
            lnm_h, lnm_l, DF, 0, lmw_h, lmw_l, DF, 0,
            out + (long)c*16000, nullptr, nullptr, VV, 0,
            RR, 16000, DF, nullptr, nullptr, 0, nullptr);
    }
}

// Round 2
// 7153.082 us; speedup vs baseline: 2.5973x; 1.0451x over previous
//
#include <hip/hip_runtime.h>

#define BB 2
#define LL 2048
#define DS 128
#define DF 1024
#define NH 4
#define NP 3
#define VV 32000
#define FFH 4096   // FFN_MULT*DF
#define CTXD 2048  // 2*DF
#define RR (BB*LL) // 4096
#define NHDF (NH*DF)

enum { EPI_NONE=0, EPI_TANH=1, EPI_GELU=2, EPI_EXPM=3 };

// =====================================================================
// Legacy fp32 SIMT GEMM (kept: small-N gemms + full fallback path)
// =====================================================================
#define BM 128
#define BN 128
#define BK 8

template<int EPI, bool BETA, bool BT, bool TRI>
__global__ __launch_bounds__(256) void gemm_f32(
    const float* __restrict__ A, int lda, long sA,
    const float* __restrict__ B, int ldb, long sB,
    float* __restrict__ C, int ldc, long sC,
    int M, int N, int K,
    const float* __restrict__ bias,
    const float* __restrict__ m2s, long sM2,
    const float* __restrict__ log_tau)
{
    __shared__ __align__(16) float As[BK][BM];
    __shared__ __align__(16) float Bs[BK][BN];
    int z = blockIdx.z;
    A += (long)z * sA; B += (long)z * sB; C += (long)z * sC;
    const float* m2p = (EPI == EPI_EXPM) ? (m2s + (long)z * sM2) : nullptr;

    int m0 = blockIdx.y * BM;
    int n0 = blockIdx.x * BN;
    int tid = threadIdx.x;
    int tx = tid & 15, ty = tid >> 4;

    float acc[8][8];
    #pragma unroll
    for (int i = 0; i < 8; i++)
        #pragma unroll
        for (int j = 0; j < 8; j++) acc[i][j] = 0.f;

    int kEnd = K;
    if (TRI) { int km = m0 + BM; kEnd = km < K ? km : K; }

    int arow = tid >> 1, akk = (tid & 1) * 4;
    for (int k0 = 0; k0 < kEnd; k0 += BK) {
        float4 av = *(const float4*)(A + (long)(m0 + arow) * lda + k0 + akk);
        As[akk+0][arow] = av.x; As[akk+1][arow] = av.y;
        As[akk+2][arow] = av.z; As[akk+3][arow] = av.w;
        if (BT) {
            float4 bv = *(const float4*)(B + (long)(n0 + arow) * ldb + k0 + akk);
            Bs[akk+0][arow] = bv.x; Bs[akk+1][arow] = bv.y;
            Bs[akk+2][arow] = bv.z; Bs[akk+3][arow] = bv.w;
        } else {
            int brow = tid >> 5, bcol = (tid & 31) * 4;
            float4 bv = *(const float4*)(B + (long)(k0 + brow) * ldb + n0 + bcol);
            *(float4*)&Bs[brow][bcol] = bv;
        }
        __syncthreads();
        #pragma unroll
        for (int kk = 0; kk < BK; kk++) {
            float a[8], b[8];
            *(float4*)&a[0] = *(const float4*)&As[kk][ty*8];
            *(float4*)&a[4] = *(const float4*)&As[kk][ty*8+4];
            *(float4*)&b[0] = *(const float4*)&Bs[kk][tx*8];
            *(float4*)&b[4] = *(const float4*)&Bs[kk][tx*8+4];
            #pragma unroll
            for (int i = 0; i < 8; i++)
                #pragma unroll
                for (int j = 0; j < 8; j++)
                    acc[i][j] = fmaf(a[i], b[j], acc[i][j]);
        }
        __syncthreads();
    }

    float scale = 0.f;
    if (EPI == EPI_EXPM) scale = -0.5f * expf(-log_tau[0]);

    #pragma unroll
    for (int i = 0; i < 8; i++) {
        int row = m0 + ty*8 + i;
        float* cp = C + (long)row * ldc + n0 + tx*8;
        float out[8];
        #pragma unroll
        for (int j = 0; j < 8; j++) {
            float v = acc[i][j];
            int col = n0 + tx*8 + j;
            if (EPI == EPI_EXPM) {
                v = expf(scale * (v + m2p[col]));
            } else {
                if (bias) v += bias[col];
                if (EPI == EPI_TANH) v = tanhf(v);
                else if (EPI == EPI_GELU) v = 0.5f*v*(1.f + erff(v*0.70710678118654752f));
            }
            out[j] = v;
        }
        if (BETA) {
            float4 c0 = *(const float4*)(cp);
            float4 c1 = *(const float4*)(cp + 4);
            out[0]+=c0.x; out[1]+=c0.y; out[2]+=c0.z; out[3]+=c0.w;
            out[4]+=c1.x; out[5]+=c1.y; out[6]+=c1.z; out[7]+=c1.w;
        }
        *(float4*)cp       = make_float4(out[0],out[1],out[2],out[3]);
        *(float4*)(cp + 4) = make_float4(out[4],out[5],out[6],out[7]);
    }
}

// =====================================================================
// Shared small kernels
// =====================================================================
__global__ __launch_bounds__(256) void embed_kernel(
    const int* __restrict__ ids, const float* __restrict__ tok_mu,
    const float* __restrict__ tok_lv, const float* __restrict__ tok_ra,
    const float* __restrict__ tok_f, const float* __restrict__ pos_mu,
    float* __restrict__ mu, float* __restrict__ iv,
    float* __restrict__ alpha, float* __restrict__ feat)
{
    int r = blockIdx.x; int l = r % LL;
    int id = ids[r];
    int tid = threadIdx.x;
    for (int i = tid; i < DS; i += 256) {
        mu[(long)r*DS + i] = tok_mu[(long)id*DS + i] + pos_mu[(long)l*DS + i];
        iv[(long)r*DS + i] = expf(-tok_lv[(long)id*DS + i]);
    }
    for (int i = tid; i < DF; i += 256)
        feat[(long)r*DF + i] = tok_f[(long)id*DF + i];
    if (tid == 0) alpha[r] = 1.f/(1.f + expf(-tok_ra[id]));
}

__global__ __launch_bounds__(256) void alpha_kernel(
    const float* __restrict__ ctx, const float* __restrict__ agw,
    const float* __restrict__ agb, float* __restrict__ alpha)
{
    int r = blockIdx.x;
    const float* xr = ctx + (long)r*CTXD;
    __shared__ float red[256];
    int tid = threadIdx.x;
    float s = 0.f;
    for (int i = tid; i < CTXD; i += 256) s += xr[i]*agw[i];
    red[tid] = s; __syncthreads();
    for (int st = 128; st > 0; st >>= 1) { if (tid < st) red[tid] += red[tid+st]; __syncthreads(); }
    if (tid == 0) alpha[r] *= 1.f/(1.f + expf(-(red[0] + agb[0])));
}

__global__ __launch_bounds__(256) void ctx_kernel(
    const float* __restrict__ feat, const float* __restrict__ meaning, float* __restrict__ ctx)
{
    long i4 = (long)blockIdx.x * 256 + threadIdx.x;
    long r = i4 >> 9;
    long c4 = i4 & 511;
    const float4* src = (c4 < 256) ? (const float4*)(feat + r*DF) + c4
                                   : (const float4*)(meaning + r*DF) + (c4 - 256);
    ((float4*)ctx)[i4] = *src;
}

// =====================================================================
// Legacy (fp32-path) builders — used only by the fallback path
// =====================================================================
__global__ __launch_bounds__(128) void qbuild_kernel(
    const float* __restrict__ mu, const float* __restrict__ iv,
    float* __restrict__ Q, float* __restrict__ m2s)
{
    int r = blockIdx.x; int d = threadIdx.x;
    float ivd = iv[(long)r*DS + d];
    float m   = mu[(long)r*DS + d];
    Q[(long)r*256 + d]       = ivd;
    Q[(long)r*256 + 128 + d] = m * ivd;
    __shared__ float red[128];
    red[d] = m*m*ivd; __syncthreads();
    for (int s = 64; s > 0; s >>= 1) { if (d < s) red[d] += red[d+s]; __syncthreads(); }
    if (d == 0) m2s[r] = red[0];
}

__global__ __launch_bounds__(128) void pbuild_kernel(const float* __restrict__ q, float* __restrict__ P)
{
    int r = blockIdx.x; int d = threadIdx.x;
    float qv = q[(long)r*DS + d];
    P[(long)r*256 + d]       = qv*qv;
    P[(long)r*256 + 128 + d] = -2.f*qv;
}

__global__ __launch_bounds__(256) void scan_weights(float* __restrict__ Kmat, const float* __restrict__ alpha)
{
    int r = blockIdx.x;
    int b = r / LL, t = r % LL;
    float* row = Kmat + (long)r * LL;
    const float* al = alpha + (long)b * LL;
    int tid = threadIdx.x;
    int lane = tid & 63, wid = tid >> 6;
    __shared__ float wtot[4];
    float carry = 1.f;
    for (int j0 = 0; j0 < LL; j0 += 256) {
        int j = j0 + tid;
        if (j0 > t) { row[j] = 0.f; continue; }
        float eff = 0.f;
        if (j <= t) eff = fminf(al[j] * row[j], 1.f - 1e-6f);
        float om = 1.f - eff;
        float incl = om;
        #pragma unroll
        for (int d = 1; d < 64; d <<= 1) {
            float v = __shfl_up(incl, d);
            if (lane >= d) incl *= v;
        }
        if (lane == 63) wtot[wid] = incl;
        float excl = __shfl_up(incl, 1);
        if (lane == 0) excl = 1.f;
        __syncthreads();
        float wpre = carry;
        for (int w = 0; w < wid; w++) wpre *= wtot[w];
        row[j] = eff * wpre * excl;
        float tot = wtot[0]*wtot[1]*wtot[2]*wtot[3];
        __syncthreads();
        carry *= tot;
    }
}

template<int C>
__global__ __launch_bounds__(256) void ln_kernel(
    const float* __restrict__ x, const float* __restrict__ g,
    const float* __restrict__ b, float* __restrict__ y)
{
    int r = blockIdx.x;
    const float* xr = x + (long)r*C;
    __shared__ float xs[C];
    __shared__ float red[256];
    int tid = threadIdx.x;
    float s = 0.f;
    for (int i = tid; i < C; i += 256) { float v = xr[i]; xs[i] = v; s += v; }
    red[tid] = s; __syncthreads();
    for (int st = 128; st > 0; st >>= 1) { if (tid < st) red[tid] += red[tid+st]; __syncthreads(); }
    float mean = red[0] / C;
    __syncthreads();
    float s2 = 0.f;
    for (int i = tid; i < C; i += 256) { float d = xs[i]-mean; s2 += d*d; }
    red[tid] = s2; __syncthreads();
    for (int st = 128; st > 0; st >>= 1) { if (tid < st) red[tid] += red[tid+st]; __syncthreads(); }
    float rs = rsqrtf(red[0]/C + 1e-5f);
    for (int i = tid; i < C; i += 256) y[(long)r*C + i] = (xs[i]-mean)*rs*g[i] + b[i];
}

// =====================================================================
// Split-bf16 (hi+lo) MFMA path.
// fp32 x = hi + lo with two RNE bf16s; a*b ~= ah*bh + ah*bl + al*bh
// =====================================================================
typedef __attribute__((ext_vector_type(8))) short bf8;   // 8 bf16 = 4 VGPRs
typedef __attribute__((ext_vector_type(4))) float f4;    // C/D frag

__device__ __forceinline__ unsigned short bf16_rne(float x){
    unsigned u = __builtin_bit_cast(unsigned, x);
    u += 0x7FFFu + ((u >> 16) & 1u);
    return (unsigned short)(u >> 16);
}
__device__ __forceinline__ float bf16f(unsigned short h){
    unsigned u = ((unsigned)h) << 16;
    return __builtin_bit_cast(float, u);
}
__device__ __forceinline__ void split2(float x, unsigned short& h, unsigned short& l){
    h = bf16_rne(x);
    l = bf16_rne(x - bf16f(h));
}
__device__ __forceinline__ f4 mfma_b(bf8 a, bf8 b, f4 c){
    return __builtin_amdgcn_mfma_f32_16x16x32_bf16(a, b, c, 0, 0, 0);
}
// async global->LDS, 16B per lane; LDS dest is wave-uniform base + lane*16
__device__ __forceinline__ void gload16(const unsigned short* g, unsigned short* l){
    __builtin_amdgcn_global_load_lds(
        (const __attribute__((address_space(1))) unsigned int*)g,
        (__attribute__((address_space(3))) unsigned int*)l, 16, 0, 0);
}

// Split-bf16 GEMM. A: [M,K] planes (Ah,Al). B: [N,K] planes (always "BT").
// 128x128 tile, BK=32, 256 thr (2x2 waves of 64x64), mfma 16x16x32 bf16.
// Staging via global_load_lds (m97 structure). XCD-chunked swizzle with
// M-fastest decode: per-XCD contiguous column chunks walk all row-blocks,
// keeping the B panel hot in that XCD's L2 (B fetched ~once from HBM).
template<int EPI, bool BETA, bool TRI, bool OSPLIT>
__global__ __launch_bounds__(256, 2) void gemm_mf(
    const unsigned short* __restrict__ Ah, const unsigned short* __restrict__ Al, int lda, long sA,
    const unsigned short* __restrict__ Bh, const unsigned short* __restrict__ Bl, int ldb, long sB,
    float* __restrict__ C, unsigned short* __restrict__ Ch, unsigned short* __restrict__ Cl,
    int ldc, long sC, int M, int N, int K,
    const float* __restrict__ bias, const float* __restrict__ m2s, long sM2,
    const float* __restrict__ log_tau)
{
    // [plane: Ah,Al,Bh,Bl][k-chunk 0..3][row 0..127][8 bf16] — 32 KiB
    // linear addr of slot s in plane p = p*8192B + s*16B  (s = c*128+row)
    __shared__ __align__(16) unsigned short lds[4][4][128][8];

    int z = blockIdx.z;
    Ah += (long)z * sA; Al += (long)z * sA;
    Bh += (long)z * sB; Bl += (long)z * sB;
    if (OSPLIT) { Ch += (long)z * sC; Cl += (long)z * sC; }
    else        { C  += (long)z * sC; }
    const float* m2p = (EPI == EPI_EXPM) ? (m2s + (long)z * sM2) : nullptr;

    // bijective XCD-chunk remap (m204), M-fastest decode
    int gx = gridDim.x, gy = gridDim.y;
    int nwg = gx * gy;
    int orig = blockIdx.y * gx + blockIdx.x;
    int qq = nwg >> 3, rmod = nwg & 7;
    int xcd = orig & 7, idx = orig >> 3;
    int wgid = (xcd < rmod ? xcd * (qq + 1) : rmod * (qq + 1) + (xcd - rmod) * qq) + idx;
    int m0 = (wgid % gy) * 128;
    int n0 = (wgid / gy) * 128;

    int tid  = threadIdx.x;
    int lane = tid & 63;
    int wave = tid >> 6;
    int wm = wave >> 1, wn = wave & 1;       // 2x2 waves, each 64x64 output
    int kc = lane >> 4, lr = lane & 15;      // frag k-chunk / row-col select

    f4 acc[4][4];
    #pragma unroll
    for (int i = 0; i < 4; i++)
        #pragma unroll
        for (int j = 0; j < 4; j++)
            #pragma unroll
            for (int r = 0; r < 4; r++) acc[i][j][r] = 0.f;

    int kEnd = K;
    if (TRI) { int km = m0 + 128; kEnd = km < K ? km : K; }

    int s0 = tid, s1 = tid + 256;            // 512 16B-slots per plane
    int row0 = s0 & 127, c0 = s0 >> 7;
    int row1 = s1 & 127, c1 = s1 >> 7;

    for (int kt = 0; kt < kEnd; kt += 32) {
        long a0 = (long)(m0 + row0) * lda + kt + c0 * 8;
        long a1 = (long)(m0 + row1) * lda + kt + c1 * 8;
        long b0 = (long)(n0 + row0) * ldb + kt + c0 * 8;
        long b1 = (long)(n0 + row1) * ldb + kt + c1 * 8;
        gload16(Ah + a0, &lds[0][c0][row0][0]);
        gload16(Ah + a1, &lds[0][c1][row1][0]);
        gload16(Al + a0, &lds[1][c0][row0][0]);
        gload16(Al + a1, &lds[1][c1][row1][0]);
        gload16(Bh + b0, &lds[2][c0][row0][0]);
        gload16(Bh + b1, &lds[2][c1][row1][0]);
        gload16(Bl + b0, &lds[3][c0][row0][0]);
        gload16(Bl + b1, &lds[3][c1][row1][0]);
        __syncthreads();   // drains vmcnt (global_load_lds) before reads

        bf8 ah[4], al4[4], bh4[4], bl4[4];
        #pragma unroll
        for (int i = 0; i < 4; i++) {
            ah[i]  = *(const bf8*)&lds[0][kc][wm*64 + i*16 + lr][0];
            al4[i] = *(const bf8*)&lds[1][kc][wm*64 + i*16 + lr][0];
            bh4[i] = *(const bf8*)&lds[2][kc][wn*64 + i*16 + lr][0];
            bl4[i] = *(const bf8*)&lds[3][kc][wn*64 + i*16 + lr][0];
        }
        #pragma unroll
        for (int i = 0; i < 4; i++)
            #pragma unroll
            for (int j = 0; j < 4; j++) {
                acc[i][j] = mfma_b(ah[i],  bh4[j], acc[i][j]);
                acc[i][j] = mfma_b(al4[i], bh4[j], acc[i][j]);
                acc[i][j] = mfma_b(ah[i],  bl4[j], acc[i][j]);
            }
        __syncthreads();
    }

    float scale = 0.f;
    if (EPI == EPI_EXPM) scale = -0.5f * expf(-log_tau[0]);
    int r0 = (lane >> 4) * 4;
    #pragma unroll
    for (int i = 0; i < 4; i++) {
        int rowb = m0 + wm*64 + i*16 + r0;
        #pragma unroll
        for (int j = 0; j < 4; j++) {
            int col = n0 + wn*64 + j*16 + lr;
            float bv = 0.f, m2v = 0.f;
            if (EPI == EPI_EXPM) m2v = m2p[col];
            else if (bias) bv = bias[col];
            #pragma unroll
            for (int r = 0; r < 4; r++) {
                long off = (long)(rowb + r) * ldc + col;
                float v = acc[i][j][r];
                if (EPI == EPI_EXPM) v = expf(scale * (v + m2v));
                else {
                    v += bv;
                    if (EPI == EPI_TANH) v = tanhf(v);
                    else if (EPI == EPI_GELU) v = 0.5f*v*(1.f + erff(v*0.70710678118654752f));
                }
                if (OSPLIT) {
                    unsigned short hh, llo; split2(v, hh, llo);
                    Ch[off] = hh; Cl[off] = llo;
                } else {
                    if (BETA) v += C[off];
                    C[off] = v;
                }
            }
        }
    }
}

// plain fp32 -> (hi,lo) bf16 planes; n must be multiple of 1024; grid = n/1024
__global__ __launch_bounds__(256) void split_kernel(
    const float* __restrict__ x, unsigned short* __restrict__ h, unsigned short* __restrict__ l)
{
    long i = (long)blockIdx.x * 256 + threadIdx.x;
    float4 v = ((const float4*)x)[i];
    ushort4 hv, lv;
    split2(v.x, hv.x, lv.x); split2(v.y, hv.y, lv.y);
    split2(v.z, hv.z, lv.z); split2(v.w, hv.w, lv.w);
    ((ushort4*)h)[i] = hv;
    ((ushort4*)l)[i] = lv;
}

// feat [RR,DF] fp32 -> featT hi/lo planes [DF,RR]; grid (DF/32, RR/32), 256 thr
__global__ __launch_bounds__(256) void tsplit_kernel(
    const float* __restrict__ x, unsigned short* __restrict__ th, unsigned short* __restrict__ tl)
{
    __shared__ float t[32][33];
    int bx = blockIdx.x, by = blockIdx.y;
    int tx = threadIdx.x & 31, ty = threadIdx.x >> 5;
    #pragma unroll
    for (int k = 0; k < 4; k++)
        t[ty + 8*k][tx] = x[(long)(by*32 + ty + 8*k)*DF + bx*32 + tx];
    __syncthreads();
    #pragma unroll
    for (int k = 0; k < 4; k++) {
        float v = t[tx][ty + 8*k];
        unsigned short hh, llo; split2(v, hh, llo);
        long o = (long)(bx*32 + ty + 8*k)*RR + by*32 + tx;
        th[o] = hh; tl[o] = llo;
    }
}

__global__ __launch_bounds__(128) void qbuild_mf(
    const float* __restrict__ mu, const float* __restrict__ iv,
    unsigned short* __restrict__ Qh, unsigned short* __restrict__ Ql,
    float* __restrict__ m2s)
{
    int r = blockIdx.x; int d = threadIdx.x;
    float ivd = iv[(long)r*DS + d];
    float m   = mu[(long)r*DS + d];
    unsigned short hh, llo;
    split2(ivd, hh, llo);
    Qh[(long)r*256 + d] = hh;        Ql[(long)r*256 + d] = llo;
    split2(m * ivd, hh, llo);
    Qh[(long)r*256 + 128 + d] = hh;  Ql[(long)r*256 + 128 + d] = llo;
    __shared__ float red[128];
    red[d] = m*m*ivd; __syncthreads();
    for (int s = 64; s > 0; s >>= 1) { if (d < s) red[d] += red[d+s]; __syncthreads(); }
    if (d == 0) m2s[r] = red[0];
}

__global__ __launch_bounds__(128) void pbuild_mf(
    const float* __restrict__ q,
    unsigned short* __restrict__ Ph, unsigned short* __restrict__ Pl)
{
    int r = blockIdx.x; int d = threadIdx.x;
    float qv = q[(long)r*DS + d];
    unsigned short hh, llo;
    split2(qv*qv, hh, llo);
    Ph[(long)r*256 + d] = hh;        Pl[(long)r*256 + d] = llo;
    split2(-2.f*qv, hh, llo);
    Ph[(long)r*256 + 128 + d] = hh;  Pl[(long)r*256 + 128 + d] = llo;
}

// stick-breaking scan; reads fp32 K, writes hi/lo bf16 weight planes
__global__ __launch_bounds__(256) void scan_weights_mf(
    const float* __restrict__ Kmat, const float* __restrict__ alpha,
    unsigned short* __restrict__ Wh, unsigned short* __restrict__ Wl)
{
    int r = blockIdx.x;
    int b = r / LL, t = r % LL;
    const float* row = Kmat + (long)r * LL;
    unsigned short* wh = Wh + (long)r * LL;
    unsigned short* wl = Wl + (long)r * LL;
    const float* al = alpha + (long)b * LL;
    int tid = threadIdx.x;
    int lane = tid & 63, wid = tid >> 6;
    __shared__ float wtot[4];
    float carry = 1.f;
    for (int j0 = 0; j0 < LL; j0 += 256) {
        int j = j0 + tid;
        if (j0 > t) { wh[j] = 0; wl[j] = 0; continue; }
        float eff = 0.f;
        if (j <= t) eff = fminf(al[j] * row[j], 1.f - 1e-6f);
        float om = 1.f - eff;
        float incl = om;
        #pragma unroll
        for (int d = 1; d < 64; d <<= 1) {
            float v = __shfl_up(incl, d);
            if (lane >= d) incl *= v;
        }
        if (lane == 63) wtot[wid] = incl;
        float excl = __shfl_up(incl, 1);
        if (lane == 0) excl = 1.f;
        __syncthreads();
        float wpre = carry;
        for (int w = 0; w < wid; w++) wpre *= wtot[w];
        float val = eff * wpre * excl;
        unsigned short hh, llo; split2(val, hh, llo);
        wh[j] = hh; wl[j] = llo;
        float tot = wtot[0]*wtot[1]*wtot[2]*wtot[3];
        __syncthreads();
        carry *= tot;
    }
}

// layernorm -> hi/lo bf16 planes
template<int C>
__global__ __launch_bounds__(256) void ln_mf(
    const float* __restrict__ x, const float* __restrict__ g,
    const float* __restrict__ b, unsigned short* __restrict__ yh, unsigned short* __restrict__ yl)
{
    int r = blockIdx.x;
    const float* xr = x + (long)r*C;
    __shared__ float xs[C];
    __shared__ float red[256];
    int tid = threadIdx.x;
    float s = 0.f;
    for (int i = tid; i < C; i += 256) { float v = xr[i]; xs[i] = v; s += v; }
    red[tid] = s; __syncthreads();
    for (int st = 128; st > 0; st >>= 1) { if (tid < st) red[tid] += red[tid+st]; __syncthreads(); }
    float mean = red[0] / C;
    __syncthreads();
    float s2 = 0.f;
    for (int i = tid; i < C; i += 256) { float d = xs[i]-mean; s2 += d*d; }
    red[tid] = s2; __syncthreads();
    for (int st = 128; st > 0; st >>= 1) { if (tid < st) red[tid] += red[tid+st]; __syncthreads(); }
    float rs = rsqrtf(red[0]/C + 1e-5f);
    for (int i = tid; i < C; i += 256) {
        float v = (xs[i]-mean)*rs*g[i] + b[i];
        unsigned short hh, llo; split2(v, hh, llo);
        yh[(long)r*C + i] = hh; yl[(long)r*C + i] = llo;
    }
}

// =====================================================================
// Legacy launch (fallback if ws too small)
// =====================================================================
static void launch_legacy(void* const* d_in, void* d_out, void* d_ws, hipStream_t stream)
{
    const int*   token_ids = (const int*)d_in[0];
    const float* tok_mu  = (const float*)d_in[1];
    const float* tok_lv  = (const float*)d_in[2];
    const float* tok_ra  = (const float*)d_in[3];
    const float* tok_f   = (const float*)d_in[4];
    const float* pos_mu  = (const float*)d_in[5];
    const float* log_tau = (const float*)d_in[6];
    const float* qp_w = (const float*)d_in[7];
    const float* qp_b = (const float*)d_in[8];
    const float* hp_w = (const float*)d_in[9];
    const float* hp_b = (const float*)d_in[10];
    const float* mu_w = (const float*)d_in[11];
    const float* mu_b = (const float*)d_in[12];
    const float* ag_w = (const float*)d_in[13];
    const float* ag_b = (const float*)d_in[14];
    const float* ln_g = (const float*)d_in[15];
    const float* ln_b = (const float*)d_in[16];
    const float* w1 = (const float*)d_in[17];
    const float* b1 = (const float*)d_in[18];
    const float* w2 = (const float*)d_in[19];
    const float* b2 = (const float*)d_in[20];
    const float* lnf_g = (const float*)d_in[21];
    const float* lnf_b = (const float*)d_in[22];
    const float* lm_w  = (const float*)d_in[23];
    float* out = (float*)d_out;

    float* ws      = (float*)d_ws;
    float* mu      = ws;
    float* iv      = mu + 524288;
    float* alpha   = iv + 524288;
    float* m2s     = alpha + 4096;
    float* q       = m2s + 4096;
    float* P       = q + 524288;
    float* Q       = P + 1048576;
    float* feat    = Q + 1048576;
    float* meaning = feat + 4194304;
    float* head_m  = meaning + 4194304;
    float* ctx     = head_m + 4194304;
    float* Kbuf    = ctx + 8388608;
    float* h1  = Kbuf;
    float* h2  = head_m;
    float* lnm = head_m;

    const int R = BB * LL;

    embed_kernel<<<R, 256, 0, stream>>>(token_ids, tok_mu, tok_lv, tok_ra, tok_f, pos_mu,
                                        mu, iv, alpha, feat);

    for (int p = 0; p < NP; p++) {
        qbuild_kernel<<<R, 128, 0, stream>>>(mu, iv, Q, m2s);
        for (int h = 0; h < NH; h++) {
            dim3 g1(DS/BN, R/BM, 1);
            gemm_f32<EPI_NONE,false,true,false><<<g1,256,0,stream>>>(
                mu, DS, 0, qp_w + (long)h*DS*DS, DS, 0, q, DS, 0,
                R, DS, DS, qp_b + h*DS, nullptr, 0, nullptr);
            pbuild_kernel<<<R, 128, 0, stream>>>(q, P);
            dim3 g2(LL/BN, LL/BM, BB);
            gemm_f32<EPI_EXPM,false,true,false><<<g2,256,0,stream>>>(
                P, 256, (long)LL*256, Q, 256, (long)LL*256, Kbuf, LL, (long)LL*LL,
                LL, LL, 256, nullptr, m2s, LL, log_tau);
            scan_weights<<<R, 256, 0, stream>>>(Kbuf, alpha);
            dim3 g3(DF/BN, LL/BM, BB);
            gemm_f32<EPI_NONE,false,false,true><<<g3,256,0,stream>>>(
                Kbuf, LL, (long)LL*LL, feat, DF, (long)LL*DF, head_m, DF, (long)LL*DF,
                LL, DF, LL, nullptr, nullptr, 0, nullptr);
            dim3 g4(DF/BN, R/BM, 1);
            if (h == 0)
                gemm_f32<EPI_NONE,false,true,false><<<g4,256,0,stream>>>(
                    head_m, DF, 0, hp_w + (long)h*DF, NH*DF, 0, meaning, DF, 0,
                    R, DF, DF, hp_b, nullptr, 0, nullptr);
            else
                gemm_f32<EPI_NONE,true,true,false><<<g4,256,0,stream>>>(
                    head_m, DF, 0, hp_w + (long)h*DF, NH*DF, 0, meaning, DF, 0,
                    R, DF, DF, nullptr, nullptr, 0, nullptr);
        }
        if (p < NP - 1) {
            ctx_kernel<<<(R*CTXD/4)/256, 256, 0, stream>>>(feat, meaning, ctx);
            dim3 g5(DS/BN, R/BM, 1);
            gemm_f32<EPI_TANH,true,true,false><<<g5,256,0,stream>>>(
                ctx, CTXD, 0, mu_w + (long)p*DS*CTXD, CTXD, 0, mu, DS, 0,
                R, DS, CTXD, mu_b + p*DS, nullptr, 0, nullptr);
            alpha_kernel<<<R, 256, 0, stream>>>(ctx, ag_w + (long)p*CTXD, ag_b + p, alpha);
            ln_kernel<CTXD><<<R, 256, 0, stream>>>(ctx, ln_g + (long)p*CTXD, ln_b + (long)p*CTXD, h1);
            for (int c = 0; c < 4; c++) {
                long ro = (long)c * 1024;
                dim3 g6(FFH/BN, 1024/BM, 1);
                gemm_f32<EPI_GELU,false,true,false><<<g6,256,0,stream>>>(
                    h1 + ro*CTXD, CTXD, 0, w1 + (long)p*FFH*CTXD, CTXD, 0, h2, FFH, 0,
                    1024, FFH, CTXD, b1 + (long)p*FFH, nullptr, 0, nullptr);
                dim3 g7(DF/BN, 1024/BM, 1);
                gemm_f32<EPI_NONE,true,true,false><<<g7,256,0,stream>>>(
                    h2, FFH, 0, w2 + (long)p*DF*FFH, FFH, 0, feat + ro*DF, DF, 0,
                    1024, DF, FFH, b2 + (long)p*DF, nullptr, 0, nullptr);
            }
        }
    }

    ln_kernel<DF><<<R, 256, 0, stream>>>(meaning, lnf_g, lnf_b, lnm);
    dim3 g8(VV/BN, R/BM, 1);
    gemm_f32<EPI_NONE,false,true,false><<<g8,256,0,stream>>>(
        lnm, DF, 0, lm_w, DF, 0, out, VV, 0,
        R, VV, DF, nullptr, nullptr, 0, nullptr);
}

// =====================================================================
// MFMA launch
// =====================================================================
extern "C" void kernel_launch(void* const* d_in, const int* in_sizes, int n_in,
                              void* d_out, int out_size, void* d_ws, size_t ws_size,
                              hipStream_t stream)
{
    const size_t WS_NEED = 174096384;
    if (ws_size < WS_NEED) {
        launch_legacy(d_in, d_out, d_ws, stream);
        return;
    }

    const int*   token_ids = (const int*)d_in[0];
    const float* tok_mu  = (const float*)d_in[1];
    const float* tok_lv  = (const float*)d_in[2];
    const float* tok_ra  = (const float*)d_in[3];
    const float* tok_f   = (const float*)d_in[4];
    const float* pos_mu  = (const float*)d_in[5];
    const float* log_tau = (const float*)d_in[6];
    const float* qp_w = (const float*)d_in[7];
    const float* qp_b = (const float*)d_in[8];
    const float* hp_w = (const float*)d_in[9];
    const float* hp_b = (const float*)d_in[10];
    const float* mu_w = (const float*)d_in[11];
    const float* mu_b = (const float*)d_in[12];
    const float* ag_w = (const float*)d_in[13];
    const float* ag_b = (const float*)d_in[14];
    const float* ln_g = (const float*)d_in[15];
    const float* ln_b = (const float*)d_in[16];
    const float* w1 = (const float*)d_in[17];
    const float* b1 = (const float*)d_in[18];
    const float* w2 = (const float*)d_in[19];
    const float* b2 = (const float*)d_in[20];
    const float* lnf_g = (const float*)d_in[21];
    const float* lnf_b = (const float*)d_in[22];
    const float* lm_w  = (const float*)d_in[23];
    float* out = (float*)d_out;

    // ---- fp32 region ----
    float* ws      = (float*)d_ws;
    float* mu      = ws;                       // 524288
    float* iv      = mu + 524288;              // 524288
    float* alpha   = iv + 524288;              // 4096
    float* m2s     = alpha + 4096;             // 4096
    float* q       = m2s + 4096;               // 524288
    float* feat    = q + 524288;               // 4194304
    float* meaning = feat + 4194304;           // 4194304
    float* ctxK    = meaning + 4194304;        // 8388608  union: ctx / Kbuf
    float* Kbuf = ctxK;
    float* ctx  = ctxK;

    // ---- bf16 pool (50,331,648 ushorts), phase-aliased ----
    unsigned short* pool = (unsigned short*)(ctxK + 8388608);
    // head phase
    unsigned short* featT_h = pool;                 // 4194304  [DF,RR]
    unsigned short* featT_l = pool + 4194304;
    unsigned short* hpw_h   = pool + 8388608;       // 4194304  [DF,NHDF]
    unsigned short* hpw_l   = pool + 12582912;
    unsigned short* P_h     = pool + 16777216;      // 1048576  [RR,256]
    unsigned short* P_l     = pool + 17825792;
    unsigned short* Q_h     = pool + 18874368;      // 1048576
    unsigned short* Q_l     = pool + 19922944;
    unsigned short* W_h     = pool + 20971520;      // 8388608  [BB,LL,LL]
    unsigned short* W_l     = pool + 29360128;
    unsigned short* hm_h    = pool + 37748736;      // 4194304  [RR,DF]
    unsigned short* hm_l    = pool + 41943040;
    // ffn phase (aliases head phase)
    unsigned short* h1_h  = pool;                   // 4194304  [2048,CTXD]
    unsigned short* h1_l  = pool + 4194304;
    unsigned short* w1s_h = pool + 8388608;         // 8388608  [FFH,CTXD]
    unsigned short* w1s_l = pool + 16777216;
    unsigned short* h2_h  = pool + 25165824;        // 8388608  [2048,FFH]
    unsigned short* h2_l  = pool + 33554432;
    unsigned short* w2s_h = pool + 41943040;        // 4194304  [DF,FFH]
    unsigned short* w2s_l = pool + 46137344;
    // end phase
    unsigned short* lnm_h = pool;                   // 4194304  [RR,DF]
    unsigned short* lnm_l = pool + 4194304;
    unsigned short* lmw_h = pool + 8388608;         // 16384000 [16000,DF]
    unsigned short* lmw_l = pool + 24772608;

    embed_kernel<<<RR, 256, 0, stream>>>(token_ids, tok_mu, tok_lv, tok_ra, tok_f, pos_mu,
                                         mu, iv, alpha, feat);

    for (int p = 0; p < NP; p++) {
        tsplit_kernel<<<dim3(DF/32, RR/32), 256, 0, stream>>>(feat, featT_h, featT_l);
        split_kernel<<<(DF*NHDF)/1024, 256, 0, stream>>>(hp_w, hpw_h, hpw_l);
        qbuild_mf<<<RR, 128, 0, stream>>>(mu, iv, Q_h, Q_l, m2s);
        for (int h = 0; h < NH; h++) {
            // q = mu @ qp_w[h]^T + qp_b[h]   (small, fp32 SIMT)
            dim3 g1(DS/BN, RR/BM, 1);
            gemm_f32<EPI_NONE,false,true,false><<<g1,256,0,stream>>>(
                mu, DS, 0, qp_w + (long)h*DS*DS, DS, 0, q, DS, 0,
                RR, DS, DS, qp_b + h*DS, nullptr, 0, nullptr);
            pbuild_mf<<<RR, 128, 0, stream>>>(q, P_h, P_l);
            // K = exp(-0.5*(P@Q^T + m2s[j])/tau), batched over b
            dim3 g2(LL/128, LL/128, BB);
            gemm_mf<EPI_EXPM,false,false,false><<<g2,256,0,stream>>>(
                P_h, P_l, 256, (long)LL*256, Q_h, Q_l, 256, (long)LL*256,
                Kbuf, nullptr, nullptr, LL, (long)LL*LL,
                LL, LL, 256, nullptr, m2s, LL, log_tau);
            scan_weights_mf<<<RR, 256, 0, stream>>>(Kbuf, alpha, W_h, W_l);
            // head_m = W @ features  (featT planes; causal k-skip) -> split planes
            dim3 g3(DF/128, LL/128, BB);
            gemm_mf<EPI_NONE,false,true,true><<<g3,256,0,stream>>>(
                W_h, W_l, LL, (long)LL*LL, featT_h, featT_l, RR, (long)LL,
                nullptr, hm_h, hm_l, DF, (long)LL*DF,
                LL, DF, LL, nullptr, nullptr, 0, nullptr);
            // meaning (+)= head_m @ hp_w[:, h*DF:(h+1)*DF]^T (+ hp_b at h==0)
            dim3 g4(DF/128, RR/128, 1);
            if (h == 0)
                gemm_mf<EPI_NONE,false,false,false><<<g4,256,0,stream>>>(
                    hm_h, hm_l, DF, 0, hpw_h + (long)h*DF, hpw_l + (long)h*DF, NHDF, 0,
                    meaning, nullptr, nullptr, DF, 0,
                    RR, DF, DF, hp_b, nullptr, 0, nullptr);
            else
                gemm_mf<EPI_NONE,true,false,false><<<g4,256,0,stream>>>(
                    hm_h, hm_l, DF, 0, hpw_h + (long)h*DF, hpw_l + (long)h*DF, NHDF, 0,
                    meaning, nullptr, nullptr, DF, 0,
                    RR, DF, DF, nullptr, nullptr, 0, nullptr);
        }
        if (p < NP - 1) {
            ctx_kernel<<<(RR*CTXD/4)/256, 256, 0, stream>>>(feat, meaning, ctx);
            // mu += tanh(ctx @ mu_w[p]^T + mu_b[p])  (N=128, fp32 SIMT)
            dim3 g5(DS/BN, RR/BM, 1);
            gemm_f32<EPI_TANH,true,true,false><<<g5,256,0,stream>>>(
                ctx, CTXD, 0, mu_w + (long)p*DS*CTXD, CTXD, 0, mu, DS, 0,
                RR, DS, CTXD, mu_b + p*DS, nullptr, 0, nullptr);
            alpha_kernel<<<RR, 256, 0, stream>>>(ctx, ag_w + (long)p*CTXD, ag_b + p, alpha);
            split_kernel<<<(FFH*CTXD)/1024, 256, 0, stream>>>(w1 + (long)p*FFH*CTXD, w1s_h, w1s_l);
            split_kernel<<<(DF*FFH)/1024, 256, 0, stream>>>(w2 + (long)p*DF*FFH, w2s_h, w2s_l);
            // FFN in 2048-row chunks
            for (int c = 0; c < 2; c++) {
                long ro = (long)c * 2048;
                ln_mf<CTXD><<<2048, 256, 0, stream>>>(
                    ctx + ro*CTXD, ln_g + (long)p*CTXD, ln_b + (long)p*CTXD, h1_h, h1_l);
                dim3 g6(FFH/128, 2048/128, 1);
                gemm_mf<EPI_GELU,false,false,true><<<g6,256,0,stream>>>(
                    h1_h, h1_l, CTXD, 0, w1s_h, w1s_l, CTXD, 0,
                    nullptr, h2_h, h2_l, FFH, 0,
                    2048, FFH, CTXD, b1 + (long)p*FFH, nullptr, 0, nullptr);
                dim3 g7(DF/128, 2048/128, 1);
                gemm_mf<EPI_NONE,true,false,false><<<g7,256,0,stream>>>(
                    h2_h, h2_l, FFH, 0, w2s_h, w2s_l, FFH, 0,
                    feat + ro*DF, nullptr, nullptr, DF, 0,
                    2048, DF, FFH, b2 + (long)p*DF, nullptr, 0, nullptr);
            }
        }
    }

    // logits = LN(meaning) @ lm_w^T, in 2 N-chunks of 16000
    ln_mf<DF><<<RR, 256, 0, stream>>>(meaning, lnf_g, lnf_b, lnm_h, lnm_l);
    for (int c = 0; c < 2; c++) {
        split_kernel<<<(16000*DF)/1024, 256, 0, stream>>>(lm_w + (long)c*16000*DF, lmw_h, lmw_l);
        dim3 g8(16000/128, RR/128, 1);
        gemm_mf<EPI_NONE,false,false,false><<<g8,256,0,stream>>>(
            lnm_h, lnm_l, DF, 0, lmw_h, lmw_l, DF, 0,
            out + (long)c*16000, nullptr, nullptr, VV, 0,
            RR, 16000, DF, nullptr, nullptr, 0, nullptr);
    }
}